// Round 1
// baseline (252.250 us; speedup 1.0000x reference)
//
#include <hip/hip_runtime.h>
#include <hip/hip_bf16.h>
#include <hip/hip_fp16.h>

#define N_NODES 10000
#define N_EDGES 160000
#define FDIM    512
#define MPAD    10112   // 79 * 128
#define NGRAPH  64
#define OUTF    128

typedef __attribute__((ext_vector_type(8))) _Float16 f16x8;
typedef __attribute__((ext_vector_type(4))) _Float16 f16x4;
typedef __attribute__((ext_vector_type(2))) _Float16 f16x2;
typedef __attribute__((ext_vector_type(4))) float    f32x4;

__device__ __forceinline__ void gload_lds16(const void* g, void* l) {
    __builtin_amdgcn_global_load_lds(
        (const __attribute__((address_space(1))) void*)g,
        (__attribute__((address_space(3))) void*)l, 16, 0, 0);
}

// ---------------- dtype detection (int64 vs int32 index buffers) ------------
__global__ void flag_kernel(const unsigned* __restrict__ raw, int* __restrict__ flag) {
    int t = threadIdx.x;                 // 64 threads
    unsigned v = raw[2 * t + 1];         // high word if int64, real data if int32
    unsigned long long b = __ballot(v != 0u);
    if (t == 0) flag[0] = (b == 0ull) ? 1 : 0;
}

__global__ void extract_edges(const unsigned* __restrict__ raw, const int* __restrict__ flag,
                              int* __restrict__ src, int* __restrict__ dst,
                              int* __restrict__ deg_cnt) {
    int e = blockIdx.x * 256 + threadIdx.x;
    if (e >= N_EDGES) return;
    int is64 = flag[0];
    unsigned s, d;
    if (is64) { s = raw[2 * e]; d = raw[2 * (N_EDGES + e)]; }
    else      { s = raw[e];     d = raw[N_EDGES + e]; }
    src[e] = (int)s; dst[e] = (int)d;
    atomicAdd(&deg_cnt[d], 1);
}

__global__ void extract_batch(const unsigned* __restrict__ raw, const int* __restrict__ flag,
                              int* __restrict__ batch32, int* __restrict__ gcnt) {
    int n = blockIdx.x * 256 + threadIdx.x;
    if (n >= N_NODES) return;
    unsigned b = flag[0] ? raw[2 * n] : raw[n];
    batch32[n] = (int)b;
    atomicAdd(&gcnt[b], 1);
}

__global__ void dinv_kernel(const int* __restrict__ deg_cnt, float* __restrict__ dinv) {
    int n = blockIdx.x * 256 + threadIdx.x;
    if (n >= N_NODES) return;
    dinv[n] = rsqrtf((float)(deg_cnt[n] + 1));   // +1 self-loop
}

// single block, 256 threads: rowptr = exclusive scan of deg_cnt; goff = scan of gcnt
__global__ void scan_kernel(const int* __restrict__ deg_cnt, int* __restrict__ rowptr,
                            int* __restrict__ fillcnt,
                            const int* __restrict__ gcnt, int* __restrict__ goff) {
    __shared__ int sums[256];
    int t = threadIdx.x;
    if (t == 0) {
        int run = 0;
        for (int g = 0; g < NGRAPH; ++g) { goff[g] = run; run += gcnt[g]; }
        goff[NGRAPH] = run;
    }
    const int CH = 40;                       // 256*40 >= 10000
    int start = t * CH, end = min(start + CH, N_NODES);
    int s = 0;
    for (int i = start; i < end; ++i) s += deg_cnt[i];
    sums[t] = s;
    __syncthreads();
    for (int off = 1; off < 256; off <<= 1) {
        int v = (t >= off) ? sums[t - off] : 0;
        __syncthreads();
        sums[t] += v;
        __syncthreads();
    }
    int pre = (t == 0) ? 0 : sums[t - 1];
    for (int i = start; i < end; ++i) {
        rowptr[i] = pre; fillcnt[i] = pre;
        pre += deg_cnt[i];
    }
    if (t == 255) rowptr[N_NODES] = pre;
}

__global__ void scatter_kernel(const int* __restrict__ src, const int* __restrict__ dst,
                               const float* __restrict__ dinv, int* __restrict__ fillcnt,
                               int* __restrict__ col, float* __restrict__ wgt) {
    int e = blockIdx.x * 256 + threadIdx.x;
    if (e >= N_EDGES) return;
    int s = src[e], d = dst[e];
    int idx = atomicAdd(&fillcnt[d], 1);
    col[idx] = s;
    wgt[idx] = dinv[s] * dinv[d];
}

// ---------------- conversions ------------------------------------------------
__global__ void convert_x(const float* __restrict__ x, _Float16* __restrict__ xh) {
    long i = (long)(blockIdx.x * 256 + threadIdx.x) * 4;   // 4 elems per thread
    long row = i >> 9;
    f16x4 o;
    if (row < N_NODES) {
        float4 v = *(const float4*)(x + i);
        o.x = (_Float16)v.x; o.y = (_Float16)v.y;
        o.z = (_Float16)v.z; o.w = (_Float16)v.w;
    } else {
        o.x = o.y = o.z = o.w = (_Float16)0.0f;
    }
    *(f16x4*)(xh + i) = o;
}

// W[k][n] (512x512 row-major) -> WT[n][k] as f16
__global__ void prep_w(const float* __restrict__ W1, const float* __restrict__ W2,
                       _Float16* __restrict__ W1T, _Float16* __restrict__ W2T) {
    int id = blockIdx.x * 256 + threadIdx.x;       // 0 .. 2*512*512-1
    int which = id >> 18;
    int r = id & 262143;
    int n = r >> 9, k = r & 511;
    const float* W  = which ? W2  : W1;
    _Float16*   T   = which ? W2T : W1T;
    T[n * 512 + k] = (_Float16)W[k * 512 + n];
}

// ---------------- GEMM: C[Mpad,512] = A[Mpad,512] @ B  (B given as Bt[n][k]) --
#define BM 128
#define BN 128
#define BK 64

__global__ __launch_bounds__(256) void gemm_f16(
    const _Float16* __restrict__ A, const _Float16* __restrict__ Bt,
    _Float16* __restrict__ C) {
    __shared__ __align__(16) _Float16 Asm[BM * BK];
    __shared__ __align__(16) _Float16 Bsm[BN * BK];
    char* As = (char*)Asm;
    char* Bs = (char*)Bsm;
    const char* Ab = (const char*)A;
    const char* Bb = (const char*)Bt;

    int tid  = threadIdx.x;
    int lane = tid & 63;
    int wave = tid >> 6;                  // 4 waves
    int wrow = wave >> 1, wcol = wave & 1;  // 2x2 grid of 64x64 sub-tiles
    int m0 = blockIdx.y * BM;
    int n0 = blockIdx.x * BN;

    f32x4 acc[4][4] = {};

    for (int kt = 0; kt < FDIM; kt += BK) {
        // stage A and B tiles: 16KB each, 4 rounds of (4 waves x 64 lanes x 16B)
        #pragma unroll
        for (int i = 0; i < 4; ++i) {
            int o   = i * 4096 + wave * 1024 + lane * 16; // linear LDS byte offset
            int row = o >> 7;                             // tile row (128B rows)
            int cb  = o & 127;
            int scb = cb ^ ((row & 7) << 4);              // inverse-swizzled source col
            gload_lds16(Ab + (size_t)(m0 + row) * 1024 + kt * 2 + scb,
                        As + i * 4096 + wave * 1024);
            gload_lds16(Bb + (size_t)(n0 + row) * 1024 + kt * 2 + scb,
                        Bs + i * 4096 + wave * 1024);
        }
        __syncthreads();   // drains vmcnt before LDS reads

        #pragma unroll
        for (int kk = 0; kk < 2; ++kk) {
            f16x8 af[4], bf[4];
            int kb = kk * 64 + ((lane >> 4) << 4);        // byte offset in row
            #pragma unroll
            for (int fm = 0; fm < 4; ++fm) {
                int r = wrow * 64 + fm * 16 + (lane & 15);
                af[fm] = *(const f16x8*)(As + r * 128 + (kb ^ ((r & 7) << 4)));
            }
            #pragma unroll
            for (int fn = 0; fn < 4; ++fn) {
                int r = wcol * 64 + fn * 16 + (lane & 15);
                bf[fn] = *(const f16x8*)(Bs + r * 128 + (kb ^ ((r & 7) << 4)));
            }
            #pragma unroll
            for (int fm = 0; fm < 4; ++fm)
                #pragma unroll
                for (int fn = 0; fn < 4; ++fn)
                    acc[fm][fn] = __builtin_amdgcn_mfma_f32_16x16x32_f16(
                        af[fm], bf[fn], acc[fm][fn], 0, 0, 0);
        }
        __syncthreads();
    }

    // C[row][col], row = m0+wrow*64+fm*16+(lane>>4)*4+r, col = n0+wcol*64+fn*16+(lane&15)
    #pragma unroll
    for (int fm = 0; fm < 4; ++fm) {
        #pragma unroll
        for (int fn = 0; fn < 4; ++fn) {
            #pragma unroll
            for (int r = 0; r < 4; ++r) {
                int row = m0 + wrow * 64 + fm * 16 + ((lane >> 4) << 2) + r;
                int cn  = n0 + wcol * 64 + fn * 16 + (lane & 15);
                C[(size_t)row * FDIM + cn] = (_Float16)acc[fm][fn][r];
            }
        }
    }
}

// ---------------- propagation: z[d] = relu( sum_e w*h[src] + dinv[d]^2*h[d] + b )
__global__ __launch_bounds__(256) void prop_kernel(
    const _Float16* __restrict__ h, const int* __restrict__ rowptr,
    const int* __restrict__ col, const float* __restrict__ wgt,
    const float* __restrict__ dinv, const float* __restrict__ bias,
    _Float16* __restrict__ z) {
    int d = blockIdx.x;
    int t = threadIdx.x;                          // features 2t, 2t+1
    float sw = dinv[d]; sw = sw * sw;
    f16x2 hv = *(const f16x2*)(h + (size_t)d * FDIM + 2 * t);
    float a0 = sw * (float)hv.x;
    float a1 = sw * (float)hv.y;
    int jb = rowptr[d], je = rowptr[d + 1];
    for (int j = jb; j < je; ++j) {
        int s = col[j];
        float w = wgt[j];
        f16x2 v = *(const f16x2*)(h + (size_t)s * FDIM + 2 * t);
        a0 += w * (float)v.x;
        a1 += w * (float)v.y;
    }
    a0 = fmaxf(a0 + bias[2 * t], 0.0f);
    a1 = fmaxf(a1 + bias[2 * t + 1], 0.0f);
    f16x2 o; o.x = (_Float16)a0; o.y = (_Float16)a1;
    *(f16x2*)(z + (size_t)d * FDIM + 2 * t) = o;
}

// ---------------- pooling + final linear ------------------------------------
__global__ void pool_kernel(const _Float16* __restrict__ z, const int* __restrict__ goff,
                            float* __restrict__ pooled) {
    int g = blockIdx.x >> 3, c = blockIdx.x & 7;
    int t = threadIdx.x;
    float a0 = 0.f, a1 = 0.f;
    int e = goff[g + 1];
    for (int n = goff[g] + c; n < e; n += 8) {
        f16x2 v = *(const f16x2*)(z + (size_t)n * FDIM + 2 * t);
        a0 += (float)v.x;
        a1 += (float)v.y;
    }
    atomicAdd(&pooled[g * FDIM + 2 * t],     a0);
    atomicAdd(&pooled[g * FDIM + 2 * t + 1], a1);
}

__global__ void final_kernel(const float* __restrict__ pooled, const float* __restrict__ Wlin,
                             const float* __restrict__ blin, float* __restrict__ out) {
    __shared__ float p[FDIM];
    int g = blockIdx.x, t = threadIdx.x;          // 128 threads
    for (int i = t; i < FDIM; i += 128) p[i] = pooled[g * FDIM + i];
    __syncthreads();
    float acc = blin[t];
    for (int k = 0; k < FDIM; ++k) acc += p[k] * Wlin[k * OUTF + t];
    out[g * OUTF + t] = acc;
}

// ---------------- launch -----------------------------------------------------
extern "C" void kernel_launch(void* const* d_in, const int* in_sizes, int n_in,
                              void* d_out, int out_size, void* d_ws, size_t ws_size,
                              hipStream_t stream) {
    const float*    x    = (const float*)d_in[0];
    const float*    W1   = (const float*)d_in[1];
    const float*    b1   = (const float*)d_in[2];
    const float*    W2   = (const float*)d_in[3];
    const float*    b2   = (const float*)d_in[4];
    const float*    Wlin = (const float*)d_in[5];
    const float*    blin = (const float*)d_in[6];
    const unsigned* eidx = (const unsigned*)d_in[7];
    const unsigned* bat  = (const unsigned*)d_in[8];
    float* out = (float*)d_out;

    char* w = (char*)d_ws;
    auto alloc = [&](size_t sz) { char* p = w; w += (sz + 255) & ~255ull; return p; };
    _Float16* buf0 = (_Float16*)alloc((size_t)MPAD * FDIM * 2);  // xh, then h2
    _Float16* buf1 = (_Float16*)alloc((size_t)MPAD * FDIM * 2);  // h1, then z2
    _Float16* buf2 = (_Float16*)alloc((size_t)MPAD * FDIM * 2);  // z1
    _Float16* W1T  = (_Float16*)alloc(512 * 512 * 2);
    _Float16* W2T  = (_Float16*)alloc(512 * 512 * 2);
    int*   src32   = (int*)alloc(N_EDGES * 4);
    int*   dst32   = (int*)alloc(N_EDGES * 4);
    int*   colA    = (int*)alloc(N_EDGES * 4);
    float* wgtA    = (float*)alloc(N_EDGES * 4);
    int*   rowptr  = (int*)alloc((N_NODES + 1) * 4);
    int*   fillcnt = (int*)alloc(N_NODES * 4);
    int*   deg_cnt = (int*)alloc(N_NODES * 4);
    float* dinv    = (float*)alloc(N_NODES * 4);
    int*   batch32 = (int*)alloc(N_NODES * 4);
    int*   gcnt    = (int*)alloc(NGRAPH * 4);
    int*   goff    = (int*)alloc((NGRAPH + 1) * 4);
    int*   flag    = (int*)alloc(16);

    hipMemsetAsync(d_out, 0, (size_t)(NGRAPH * FDIM + NGRAPH * OUTF) * 4, stream);
    hipMemsetAsync(deg_cnt, 0, N_NODES * 4, stream);
    hipMemsetAsync(gcnt, 0, NGRAPH * 4, stream);

    flag_kernel<<<1, 64, 0, stream>>>(eidx, flag);
    extract_edges<<<(N_EDGES + 255) / 256, 256, 0, stream>>>(eidx, flag, src32, dst32, deg_cnt);
    extract_batch<<<(N_NODES + 255) / 256, 256, 0, stream>>>(bat, flag, batch32, gcnt);
    dinv_kernel<<<(N_NODES + 255) / 256, 256, 0, stream>>>(deg_cnt, dinv);
    scan_kernel<<<1, 256, 0, stream>>>(deg_cnt, rowptr, fillcnt, gcnt, goff);
    scatter_kernel<<<(N_EDGES + 255) / 256, 256, 0, stream>>>(src32, dst32, dinv, fillcnt, colA, wgtA);

    convert_x<<<(MPAD * FDIM / 4 + 255) / 256, 256, 0, stream>>>(x, buf0);
    prep_w<<<(2 * 512 * 512) / 256, 256, 0, stream>>>(W1, W2, W1T, W2T);

    dim3 ggrid(FDIM / BN, MPAD / BM);
    gemm_f16<<<ggrid, 256, 0, stream>>>(buf0, W1T, buf1);                 // h1 = x@W1
    prop_kernel<<<N_NODES, 256, 0, stream>>>(buf1, rowptr, colA, wgtA, dinv, b1, buf2); // z1
    gemm_f16<<<ggrid, 256, 0, stream>>>(buf2, W2T, buf0);                 // h2 = z1@W2
    prop_kernel<<<N_NODES, 256, 0, stream>>>(buf0, rowptr, colA, wgtA, dinv, b2, buf1); // z2

    pool_kernel<<<NGRAPH * 8, 256, 0, stream>>>(buf1, goff, out);
    final_kernel<<<NGRAPH, 128, 0, stream>>>(out, Wlin, blin, out + NGRAPH * FDIM);
}

// Round 2
// 205.421 us; speedup vs baseline: 1.2280x; 1.2280x over previous
//
#include <hip/hip_runtime.h>
#include <hip/hip_bf16.h>
#include <hip/hip_fp16.h>

#define N_NODES 10000
#define N_EDGES 160000
#define FDIM    512
#define MPAD    10112   // 79 * 128
#define NGRAPH  64
#define OUTF    128

typedef __attribute__((ext_vector_type(8))) _Float16 f16x8;
typedef __attribute__((ext_vector_type(4))) _Float16 f16x4;
typedef __attribute__((ext_vector_type(2))) _Float16 f16x2;
typedef __attribute__((ext_vector_type(4))) float    f32x4;

__device__ __forceinline__ void gload_lds16(const void* g, void* l) {
    __builtin_amdgcn_global_load_lds(
        (const __attribute__((address_space(1))) void*)g,
        (__attribute__((address_space(3))) void*)l, 16, 0, 0);
}

// ---------------- dtype detection (int64 vs int32 index buffers) ------------
__global__ void flag_kernel(const unsigned* __restrict__ raw, int* __restrict__ flag) {
    int t = threadIdx.x;                 // 64 threads
    unsigned v = raw[2 * t + 1];         // high word if int64, real data if int32
    unsigned long long b = __ballot(v != 0u);
    if (t == 0) flag[0] = (b == 0ull) ? 1 : 0;
}

__global__ void extract_edges(const unsigned* __restrict__ raw, const int* __restrict__ flag,
                              int* __restrict__ src, int* __restrict__ dst,
                              int* __restrict__ deg_cnt) {
    int e = blockIdx.x * 256 + threadIdx.x;
    if (e >= N_EDGES) return;
    int is64 = flag[0];
    unsigned s, d;
    if (is64) { s = raw[2 * e]; d = raw[2 * (N_EDGES + e)]; }
    else      { s = raw[e];     d = raw[N_EDGES + e]; }
    src[e] = (int)s; dst[e] = (int)d;
    atomicAdd(&deg_cnt[d], 1);
}

// batch is sorted -> graph boundaries by binary search; no atomics.
__global__ void goff_kernel(const unsigned* __restrict__ raw, const int* __restrict__ flag,
                            int* __restrict__ goff) {
    int g = threadIdx.x;                 // 128 threads, g in [0, NGRAPH]
    if (g > NGRAPH) return;
    int is64 = flag[0];
    int lo = 0, hi = N_NODES;
    while (lo < hi) {
        int mid = (lo + hi) >> 1;
        int b = (int)(is64 ? raw[2 * mid] : raw[mid]);
        if (b < g) lo = mid + 1; else hi = mid;
    }
    goff[g] = lo;
}

__global__ void dinv_kernel(const int* __restrict__ deg_cnt, float* __restrict__ dinv) {
    int n = blockIdx.x * 256 + threadIdx.x;
    if (n >= N_NODES) return;
    dinv[n] = rsqrtf((float)(deg_cnt[n] + 1));   // +1 self-loop
}

// single block, 256 threads: rowptr = exclusive scan of deg_cnt
__global__ void scan_kernel(const int* __restrict__ deg_cnt, int* __restrict__ rowptr,
                            int* __restrict__ fillcnt) {
    __shared__ int sums[256];
    int t = threadIdx.x;
    const int CH = 40;                       // 256*40 >= 10000
    int start = t * CH, end = min(start + CH, N_NODES);
    int s = 0;
    for (int i = start; i < end; ++i) s += deg_cnt[i];
    sums[t] = s;
    __syncthreads();
    for (int off = 1; off < 256; off <<= 1) {
        int v = (t >= off) ? sums[t - off] : 0;
        __syncthreads();
        sums[t] += v;
        __syncthreads();
    }
    int pre = (t == 0) ? 0 : sums[t - 1];
    for (int i = start; i < end; ++i) {
        rowptr[i] = pre; fillcnt[i] = pre;
        pre += deg_cnt[i];
    }
    if (t == 255) rowptr[N_NODES] = pre;
}

__global__ void scatter_kernel(const int* __restrict__ src, const int* __restrict__ dst,
                               const float* __restrict__ dinv, int* __restrict__ fillcnt,
                               int* __restrict__ col, float* __restrict__ wgt) {
    int e = blockIdx.x * 256 + threadIdx.x;
    if (e >= N_EDGES) return;
    int s = src[e], d = dst[e];
    int idx = atomicAdd(&fillcnt[d], 1);
    col[idx] = s;
    wgt[idx] = dinv[s] * dinv[d];
}

// ---------------- conversions ------------------------------------------------
__global__ void convert_x(const float* __restrict__ x, _Float16* __restrict__ xh) {
    long i = (long)(blockIdx.x * 256 + threadIdx.x) * 4;   // 4 elems per thread
    long row = i >> 9;
    f16x4 o;
    if (row < N_NODES) {
        float4 v = *(const float4*)(x + i);
        o.x = (_Float16)v.x; o.y = (_Float16)v.y;
        o.z = (_Float16)v.z; o.w = (_Float16)v.w;
    } else {
        o.x = o.y = o.z = o.w = (_Float16)0.0f;
    }
    *(f16x4*)(xh + i) = o;
}

// W[k][n] (512x512 row-major) -> WT[n][k] as f16, LDS tile transpose
__global__ __launch_bounds__(256) void prep_w(
    const float* __restrict__ W1, const float* __restrict__ W2,
    _Float16* __restrict__ W1T, _Float16* __restrict__ W2T) {
    __shared__ float tile[64][65];
    const float* W = blockIdx.z ? W2 : W1;
    _Float16*   T  = blockIdx.z ? W2T : W1T;
    int r0 = blockIdx.y * 64, c0 = blockIdx.x * 64;
    int t = threadIdx.x;
    int col = t & 63, rr = t >> 6;
    #pragma unroll
    for (int i = 0; i < 16; ++i) {
        int row = i * 4 + rr;
        tile[row][col] = W[(size_t)(r0 + row) * 512 + c0 + col];   // coalesced read
    }
    __syncthreads();
    #pragma unroll
    for (int i = 0; i < 16; ++i) {
        int orow = i * 4 + rr;                                     // output row = orig col
        T[(size_t)(c0 + orow) * 512 + r0 + col] = (_Float16)tile[col][orow]; // coalesced write
    }
}

// ---------------- GEMM: C[Mpad,512] = A[Mpad,512] @ B  (B given as Bt[n][k]) --
#define BM 128
#define BN 128
#define BK 64

__global__ __launch_bounds__(256) void gemm_f16(
    const _Float16* __restrict__ A, const _Float16* __restrict__ Bt,
    _Float16* __restrict__ C) {
    __shared__ __align__(16) _Float16 Asm[BM * BK];
    __shared__ __align__(16) _Float16 Bsm[BN * BK];
    char* As = (char*)Asm;
    char* Bs = (char*)Bsm;
    const char* Ab = (const char*)A;
    const char* Bb = (const char*)Bt;

    int tid  = threadIdx.x;
    int lane = tid & 63;
    int wave = tid >> 6;                  // 4 waves
    int wrow = wave >> 1, wcol = wave & 1;  // 2x2 grid of 64x64 sub-tiles
    int m0 = blockIdx.y * BM;
    int n0 = blockIdx.x * BN;

    f32x4 acc[4][4] = {};

    for (int kt = 0; kt < FDIM; kt += BK) {
        // stage A and B tiles: 16KB each, 4 rounds of (4 waves x 64 lanes x 16B)
        #pragma unroll
        for (int i = 0; i < 4; ++i) {
            int o   = i * 4096 + wave * 1024 + lane * 16; // linear LDS byte offset
            int row = o >> 7;                             // tile row (128B rows)
            int cb  = o & 127;
            int scb = cb ^ ((row & 7) << 4);              // inverse-swizzled source col
            gload_lds16(Ab + (size_t)(m0 + row) * 1024 + kt * 2 + scb,
                        As + i * 4096 + wave * 1024);
            gload_lds16(Bb + (size_t)(n0 + row) * 1024 + kt * 2 + scb,
                        Bs + i * 4096 + wave * 1024);
        }
        __syncthreads();   // drains vmcnt before LDS reads

        #pragma unroll
        for (int kk = 0; kk < 2; ++kk) {
            f16x8 af[4], bf[4];
            int kb = kk * 64 + ((lane >> 4) << 4);        // byte offset in row
            #pragma unroll
            for (int fm = 0; fm < 4; ++fm) {
                int r = wrow * 64 + fm * 16 + (lane & 15);
                af[fm] = *(const f16x8*)(As + r * 128 + (kb ^ ((r & 7) << 4)));
            }
            #pragma unroll
            for (int fn = 0; fn < 4; ++fn) {
                int r = wcol * 64 + fn * 16 + (lane & 15);
                bf[fn] = *(const f16x8*)(Bs + r * 128 + (kb ^ ((r & 7) << 4)));
            }
            #pragma unroll
            for (int fm = 0; fm < 4; ++fm)
                #pragma unroll
                for (int fn = 0; fn < 4; ++fn)
                    acc[fm][fn] = __builtin_amdgcn_mfma_f32_16x16x32_f16(
                        af[fm], bf[fn], acc[fm][fn], 0, 0, 0);
        }
        __syncthreads();
    }

    // C[row][col], row = m0+wrow*64+fm*16+(lane>>4)*4+r, col = n0+wcol*64+fn*16+(lane&15)
    #pragma unroll
    for (int fm = 0; fm < 4; ++fm) {
        #pragma unroll
        for (int fn = 0; fn < 4; ++fn) {
            #pragma unroll
            for (int r = 0; r < 4; ++r) {
                int row = m0 + wrow * 64 + fm * 16 + ((lane >> 4) << 2) + r;
                int cn  = n0 + wcol * 64 + fn * 16 + (lane & 15);
                C[(size_t)row * FDIM + cn] = (_Float16)acc[fm][fn][r];
            }
        }
    }
}

// ---------------- propagation: z[d] = relu( sum_e w*h[src] + dinv[d]^2*h[d] + b )
__global__ __launch_bounds__(256) void prop_kernel(
    const _Float16* __restrict__ h, const int* __restrict__ rowptr,
    const int* __restrict__ col, const float* __restrict__ wgt,
    const float* __restrict__ dinv, const float* __restrict__ bias,
    _Float16* __restrict__ z) {
    int d = blockIdx.x;
    int t = threadIdx.x;                          // features 2t, 2t+1
    float sw = dinv[d]; sw = sw * sw;
    f16x2 hv = *(const f16x2*)(h + (size_t)d * FDIM + 2 * t);
    float a0 = sw * (float)hv.x;
    float a1 = sw * (float)hv.y;
    int jb = rowptr[d], je = rowptr[d + 1];
    for (int j = jb; j < je; ++j) {
        int s = col[j];
        float w = wgt[j];
        f16x2 v = *(const f16x2*)(h + (size_t)s * FDIM + 2 * t);
        a0 += w * (float)v.x;
        a1 += w * (float)v.y;
    }
    a0 = fmaxf(a0 + bias[2 * t], 0.0f);
    a1 = fmaxf(a1 + bias[2 * t + 1], 0.0f);
    f16x2 o; o.x = (_Float16)a0; o.y = (_Float16)a1;
    *(f16x2*)(z + (size_t)d * FDIM + 2 * t) = o;
}

// ---------------- pooling + final linear ------------------------------------
__global__ void pool_kernel(const _Float16* __restrict__ z, const int* __restrict__ goff,
                            float* __restrict__ pooled) {
    int g = blockIdx.x >> 3, c = blockIdx.x & 7;
    int t = threadIdx.x;
    float a0 = 0.f, a1 = 0.f;
    int e = goff[g + 1];
    for (int n = goff[g] + c; n < e; n += 8) {
        f16x2 v = *(const f16x2*)(z + (size_t)n * FDIM + 2 * t);
        a0 += (float)v.x;
        a1 += (float)v.y;
    }
    atomicAdd(&pooled[g * FDIM + 2 * t],     a0);
    atomicAdd(&pooled[g * FDIM + 2 * t + 1], a1);
}

__global__ void final_kernel(const float* __restrict__ pooled, const float* __restrict__ Wlin,
                             const float* __restrict__ blin, float* __restrict__ out) {
    __shared__ float p[FDIM];
    int g = blockIdx.x, t = threadIdx.x;          // 128 threads
    for (int i = t; i < FDIM; i += 128) p[i] = pooled[g * FDIM + i];
    __syncthreads();
    float acc = blin[t];
    for (int k = 0; k < FDIM; ++k) acc += p[k] * Wlin[k * OUTF + t];
    out[g * OUTF + t] = acc;
}

// ---------------- launch -----------------------------------------------------
extern "C" void kernel_launch(void* const* d_in, const int* in_sizes, int n_in,
                              void* d_out, int out_size, void* d_ws, size_t ws_size,
                              hipStream_t stream) {
    const float*    x    = (const float*)d_in[0];
    const float*    W1   = (const float*)d_in[1];
    const float*    b1   = (const float*)d_in[2];
    const float*    W2   = (const float*)d_in[3];
    const float*    b2   = (const float*)d_in[4];
    const float*    Wlin = (const float*)d_in[5];
    const float*    blin = (const float*)d_in[6];
    const unsigned* eidx = (const unsigned*)d_in[7];
    const unsigned* bat  = (const unsigned*)d_in[8];
    float* out = (float*)d_out;

    char* w = (char*)d_ws;
    auto alloc = [&](size_t sz) { char* p = w; w += (sz + 255) & ~255ull; return p; };
    _Float16* buf0 = (_Float16*)alloc((size_t)MPAD * FDIM * 2);  // xh, then h2
    _Float16* buf1 = (_Float16*)alloc((size_t)MPAD * FDIM * 2);  // h1, then z2
    _Float16* buf2 = (_Float16*)alloc((size_t)MPAD * FDIM * 2);  // z1
    _Float16* W1T  = (_Float16*)alloc(512 * 512 * 2);
    _Float16* W2T  = (_Float16*)alloc(512 * 512 * 2);
    int*   src32   = (int*)alloc(N_EDGES * 4);
    int*   dst32   = (int*)alloc(N_EDGES * 4);
    int*   colA    = (int*)alloc(N_EDGES * 4);
    float* wgtA    = (float*)alloc(N_EDGES * 4);
    int*   rowptr  = (int*)alloc((N_NODES + 1) * 4);
    int*   fillcnt = (int*)alloc(N_NODES * 4);
    int*   deg_cnt = (int*)alloc(N_NODES * 4);
    float* dinv    = (float*)alloc(N_NODES * 4);
    int*   goff    = (int*)alloc((NGRAPH + 1) * 4);
    int*   flag    = (int*)alloc(16);

    hipMemsetAsync(d_out, 0, (size_t)(NGRAPH * FDIM + NGRAPH * OUTF) * 4, stream);
    hipMemsetAsync(deg_cnt, 0, N_NODES * 4, stream);

    flag_kernel<<<1, 64, 0, stream>>>(eidx, flag);
    extract_edges<<<(N_EDGES + 255) / 256, 256, 0, stream>>>(eidx, flag, src32, dst32, deg_cnt);
    goff_kernel<<<1, 128, 0, stream>>>(bat, flag, goff);
    dinv_kernel<<<(N_NODES + 255) / 256, 256, 0, stream>>>(deg_cnt, dinv);
    scan_kernel<<<1, 256, 0, stream>>>(deg_cnt, rowptr, fillcnt);
    scatter_kernel<<<(N_EDGES + 255) / 256, 256, 0, stream>>>(src32, dst32, dinv, fillcnt, colA, wgtA);

    convert_x<<<(MPAD * FDIM / 4 + 255) / 256, 256, 0, stream>>>(x, buf0);
    prep_w<<<dim3(8, 8, 2), 256, 0, stream>>>(W1, W2, W1T, W2T);

    dim3 ggrid(FDIM / BN, MPAD / BM);
    gemm_f16<<<ggrid, 256, 0, stream>>>(buf0, W1T, buf1);                 // h1 = x@W1
    prop_kernel<<<N_NODES, 256, 0, stream>>>(buf1, rowptr, colA, wgtA, dinv, b1, buf2); // z1
    gemm_f16<<<ggrid, 256, 0, stream>>>(buf2, W2T, buf0);                 // h2 = z1@W2
    prop_kernel<<<N_NODES, 256, 0, stream>>>(buf0, rowptr, colA, wgtA, dinv, b2, buf1); // z2

    pool_kernel<<<NGRAPH * 8, 256, 0, stream>>>(buf1, goff, out);
    final_kernel<<<NGRAPH, 128, 0, stream>>>(out, Wlin, blin, out + NGRAPH * FDIM);
}